// Round 3
// baseline (1220.753 us; speedup 1.0000x reference)
//
#include <hip/hip_runtime.h>
#include <hip/hip_bf16.h>

#define N_NODES 10000
#define N_EDGES 160000
#define DIM     128
#define NBASIS  16
#define LDT     136   // LDS row stride (bf16): +8 pad -> 2-way bank alias (free)

typedef __bf16 bf16x8 __attribute__((ext_vector_type(8)));
typedef __bf16 bf16x2 __attribute__((ext_vector_type(2)));
typedef float  f32x4  __attribute__((ext_vector_type(4)));

__device__ __forceinline__ float silu_f(float x){
  return x * (1.0f / (1.0f + __expf(-x)));
}

// ---------------------------------------------------------------------------
// Unified fused MFMA 2-layer MLP: Y = silu(X@W1+b1)@W2 + b2 [ * F(X) ] [ * sw ]
// 128-row tile, 256 thr = 4 waves; wave w owns rows [32w,32w+32).
// A/B frags load DIRECTLY from global (no staging LDS, no syncthreads);
// LDS only holds H (wave-private rows). W*t are bf16 pre-transposed [n][k].
// ---------------------------------------------------------------------------
template<bool IN_F32, bool OUT_F32, bool WITH_F, bool WITH_SW>
__global__ __launch_bounds__(256,4) void mlp_k(
    const void* __restrict__ Xv, int M,
    const __bf16* __restrict__ W1t, const float* __restrict__ b1,
    const __bf16* __restrict__ W2t, const float* __restrict__ b2,
    const __bf16* __restrict__ FW1t, const float* __restrict__ Fb1,
    const float* __restrict__ FW2v, const float* __restrict__ Fb2,
    const float* __restrict__ swv,
    void* __restrict__ Yv)
{
  __shared__ __bf16 sH[128*LDT];
  const int tid  = threadIdx.x;
  const int row0 = blockIdx.x*128;
  const int lane = tid & 63;
  const int wv   = tid >> 6;
  const int l15  = lane & 15;
  const int quad = lane >> 4;
  const int rA0  = row0 + wv*32 + l15;       // A-frag row, mi=0
  const int rA1  = rA0 + 16;                 // mi=1

  auto loadA = [&](int rowg, int kb)->bf16x8 {
    bf16x8 a;
    if constexpr (IN_F32){
      const float* X = (const float*)Xv;
      if (rowg < M){
        float4 u0 = *(const float4*)(X + (long)rowg*DIM + kb);
        float4 u1 = *(const float4*)(X + (long)rowg*DIM + kb + 4);
        a[0]=(__bf16)u0.x; a[1]=(__bf16)u0.y; a[2]=(__bf16)u0.z; a[3]=(__bf16)u0.w;
        a[4]=(__bf16)u1.x; a[5]=(__bf16)u1.y; a[6]=(__bf16)u1.z; a[7]=(__bf16)u1.w;
      } else {
        #pragma unroll
        for (int i=0;i<8;i++) a[i]=(__bf16)0.f;
      }
    } else {
      const __bf16* X = (const __bf16*)Xv;
      a = *(const bf16x8*)(X + (long)rowg*DIM + kb);
    }
    return a;
  };

  float eF[2][4];   // per-lane F-scalar for rows (mi, quad*4+r)

  if constexpr (WITH_F){
    f32x4 acc[2][8];
    #pragma unroll
    for (int mi=0;mi<2;++mi)
      #pragma unroll
      for (int ni=0;ni<8;++ni) acc[mi][ni]=(f32x4){0.f,0.f,0.f,0.f};
    #pragma unroll
    for (int kc=0;kc<4;++kc){
      int kb = kc*32 + quad*8;
      bf16x8 a0 = loadA(rA0, kb), a1 = loadA(rA1, kb);
      #pragma unroll
      for (int ni=0;ni<8;++ni){
        bf16x8 b = *(const bf16x8*)(FW1t + (long)(ni*16+l15)*DIM + kb);
        acc[0][ni] = __builtin_amdgcn_mfma_f32_16x16x32_bf16(a0,b,acc[0][ni],0,0,0);
        acc[1][ni] = __builtin_amdgcn_mfma_f32_16x16x32_bf16(a1,b,acc[1][ni],0,0,0);
      }
    }
    float fb2 = Fb2[0];
    #pragma unroll
    for (int mi=0;mi<2;++mi){
      #pragma unroll
      for (int r=0;r<4;++r){
        float p = 0.f;
        #pragma unroll
        for (int ni=0;ni<8;++ni){
          int col = ni*16 + l15;
          p += silu_f(acc[mi][ni][r] + Fb1[col]) * FW2v[col];
        }
        p += __shfl_xor(p,1); p += __shfl_xor(p,2);
        p += __shfl_xor(p,4); p += __shfl_xor(p,8);
        eF[mi][r] = p + fb2;
      }
    }
  }

  // GEMM1: H = silu(X @ W1 + b1)
  {
    f32x4 acc[2][8];
    #pragma unroll
    for (int mi=0;mi<2;++mi)
      #pragma unroll
      for (int ni=0;ni<8;++ni) acc[mi][ni]=(f32x4){0.f,0.f,0.f,0.f};
    #pragma unroll
    for (int kc=0;kc<4;++kc){
      int kb = kc*32 + quad*8;
      bf16x8 a0 = loadA(rA0, kb), a1 = loadA(rA1, kb);
      #pragma unroll
      for (int ni=0;ni<8;++ni){
        bf16x8 b = *(const bf16x8*)(W1t + (long)(ni*16+l15)*DIM + kb);
        acc[0][ni] = __builtin_amdgcn_mfma_f32_16x16x32_bf16(a0,b,acc[0][ni],0,0,0);
        acc[1][ni] = __builtin_amdgcn_mfma_f32_16x16x32_bf16(a1,b,acc[1][ni],0,0,0);
      }
    }
    #pragma unroll
    for (int mi=0;mi<2;++mi){
      #pragma unroll
      for (int ni=0;ni<8;++ni){
        int col = ni*16 + l15;
        float bb = b1[col];
        #pragma unroll
        for (int r=0;r<4;++r){
          int row = wv*32 + mi*16 + quad*4 + r;
          sH[row*LDT+col] = (__bf16)silu_f(acc[mi][ni][r] + bb);
        }
      }
    }
  }

  // sw per output row (folded switch for the r-MLP)
  float swr[2][4];
  if constexpr (WITH_SW){
    #pragma unroll
    for (int mi=0;mi<2;++mi)
      #pragma unroll
      for (int r=0;r<4;++r){
        int rowg = row0 + wv*32 + mi*16 + quad*4 + r;
        swr[mi][r] = (rowg < M) ? swv[rowg] : 0.f;
      }
  }

  // GEMM2: Y = H @ W2 + b2  (A from wave-private LDS rows -> no sync)
  {
    f32x4 acc[2][8];
    #pragma unroll
    for (int mi=0;mi<2;++mi)
      #pragma unroll
      for (int ni=0;ni<8;++ni) acc[mi][ni]=(f32x4){0.f,0.f,0.f,0.f};
    #pragma unroll
    for (int kc=0;kc<4;++kc){
      int kb = kc*32 + quad*8;
      bf16x8 a0 = *(bf16x8*)&sH[(wv*32      + l15)*LDT + kb];
      bf16x8 a1 = *(bf16x8*)&sH[(wv*32 + 16 + l15)*LDT + kb];
      #pragma unroll
      for (int ni=0;ni<8;++ni){
        bf16x8 b = *(const bf16x8*)(W2t + (long)(ni*16+l15)*DIM + kb);
        acc[0][ni] = __builtin_amdgcn_mfma_f32_16x16x32_bf16(a0,b,acc[0][ni],0,0,0);
        acc[1][ni] = __builtin_amdgcn_mfma_f32_16x16x32_bf16(a1,b,acc[1][ni],0,0,0);
      }
    }
    #pragma unroll
    for (int mi=0;mi<2;++mi){
      #pragma unroll
      for (int ni=0;ni<8;++ni){
        int col = ni*16 + l15;
        float bb = b2[col];
        #pragma unroll
        for (int r=0;r<4;++r){
          int rowg = row0 + wv*32 + mi*16 + quad*4 + r;
          if (rowg < M){
            float v = acc[mi][ni][r] + bb;
            if constexpr (WITH_F)  v *= eF[mi][r];
            if constexpr (WITH_SW) v *= swr[mi][r];
            if constexpr (OUT_F32) ((float*)Yv)[(long)rowg*DIM+col] = v;
            else                   ((__bf16*)Yv)[(long)rowg*DIM+col] = (__bf16)v;
          }
        }
      }
    }
  }
}

// ---------------------------------------------------------------------------
// Convert + transpose fp32 W[k][n] -> bf16 Wt[n][k]. One block per matrix.
// ---------------------------------------------------------------------------
struct WPtrs { const float* p[11]; };

__global__ __launch_bounds__(256) void convert_wt(WPtrs wp, __bf16* __restrict__ dst){
  __shared__ __bf16 s[128*129];
  int mat = blockIdx.x;          // t*3 + l
  int t = mat/3, l = mat%3;
  const float* src = wp.p[t] + (size_t)l*16384;
  __bf16* out = dst + (size_t)mat*16384;
  for (int it=0; it<64; ++it){
    int idx = it*256 + threadIdx.x;
    int k = idx>>7, n = idx&127;
    s[k*129+n] = (__bf16)src[idx];
  }
  __syncthreads();
  for (int it=0; it<64; ++it){
    int idx = it*256 + threadIdx.x;
    int n = idx>>7, k = idx&127;
    out[idx] = s[k*129+n];
  }
}

// row_start[n] = lower_bound(edge_src, n)  (edge_src is sorted)
__global__ void seg_offsets(const int* __restrict__ esrc, int* __restrict__ row_start){
  int t = blockIdx.x*256 + threadIdx.x;
  if (t > N_NODES) return;
  int lo = 0, hi = N_EDGES;
  while (lo < hi){ int mid = (lo+hi)>>1; if (esrc[mid] < t) lo = mid+1; else hi = mid; }
  row_start[t] = lo;
}

// xi init + fi zero
__global__ void init_nodes(const int* __restrict__ species,
                           const float* __restrict__ spW, const float* __restrict__ spB,
                           float* __restrict__ xi, float* __restrict__ fi){
  int idx = blockIdx.x*256 + threadIdx.x;   // < N*128
  int n = idx >> 7, d = idx & 127;
  xi[idx] = spW[species[n]*DIM + d] + spB[d];
  fi[n*384 + d*3 + 0] = 0.f;
  fi[n*384 + d*3 + 1] = 0.f;
  fi[n*384 + d*3 + 2] = 0.f;
}

// dir = vec/dist*sw ; rb = exp(-eta*(d-c_j)^2)
__global__ void edge_geom(const float* __restrict__ dist, const float* __restrict__ vec,
                          const float* __restrict__ swv,
                          float* __restrict__ dir, float* __restrict__ rb){
  int e = blockIdx.x*256 + threadIdx.x;
  if (e >= N_EDGES) return;
  float d = dist[e];
  float s = swv[e];
  float inv = s / d;
  dir[e*3+0] = vec[e*3+0]*inv;
  dir[e*3+1] = vec[e*3+1]*inv;
  dir[e*3+2] = vec[e*3+2]*inv;
  const float eta = (16.0f/5.0f)*(16.0f/5.0f);
  #pragma unroll
  for (int j=0;j<NBASIS;j++){
    float c = (float)j * (5.0f/15.0f);
    float t = d - c;
    rb[e*NBASIS + j] = __expf(-eta*t*t);
  }
}

// mij = ai[src]*ai[dst]*(rb@radW + radB)*sw ; 16 edges/block; bf16 in/out
__global__ __launch_bounds__(256) void mij_kernel(
    const __bf16* __restrict__ ai, const int* __restrict__ esrc, const int* __restrict__ edst,
    const float* __restrict__ swv, const float* __restrict__ rb,
    const float* __restrict__ radW, const float* __restrict__ radB,
    __bf16* __restrict__ mij)
{
  __shared__ float sRW[NBASIS*DIM];
  __shared__ float sRB[DIM];
  __shared__ float sRb[16*NBASIS];
  __shared__ int   sS[16], sD[16];
  __shared__ float sSw[16];
  int tid = threadIdx.x;
  int e0 = blockIdx.x * 16;
  #pragma unroll
  for (int i=0;i<2;i++){
    int idx4 = i*256 + tid;
    *(float4*)(sRW + idx4*4) = *(const float4*)(radW + idx4*4);
  }
  sRb[tid] = rb[e0*NBASIS + tid];
  if (tid < DIM) sRB[tid] = radB[tid];
  if (tid < 16){
    sS[tid]  = esrc[e0+tid];
    sD[tid]  = edst[e0+tid];
    sSw[tid] = swv[e0+tid];
  }
  __syncthreads();
  #pragma unroll
  for (int i=0;i<4;i++){
    int o = i*512 + tid*2;          // 2 consecutive d per thread
    int el = o >> 7, d = o & 127;
    bf16x2 as = *(const bf16x2*)(ai + (long)sS[el]*DIM + d);
    bf16x2 ad = *(const bf16x2*)(ai + (long)sD[el]*DIM + d);
    float acc0 = 0.f, acc1 = 0.f;
    #pragma unroll
    for (int j=0;j<NBASIS;j++){
      float rbv = sRb[el*NBASIS+j];
      acc0 += rbv*sRW[j*DIM+d];
      acc1 += rbv*sRW[j*DIM+d+1];
    }
    float sw_ = sSw[el];
    bf16x2 m;
    m[0] = (__bf16)((float)as[0]*(float)ad[0]*(acc0+sRB[d  ])*sw_);
    m[1] = (__bf16)((float)as[1]*(float)ad[1]*(acc1+sRB[d+1])*sw_);
    *(bf16x2*)(mij + (long)(e0+el)*DIM + d) = m;
  }
}

// xi += segment_sum(mij)
__global__ __launch_bounds__(128) void segsum_xi(const __bf16* __restrict__ mij,
                                                 const int* __restrict__ row_start,
                                                 float* __restrict__ xi){
  int n = blockIdx.x, d = threadIdx.x;
  int s0 = row_start[n], s1 = row_start[n+1];
  float s = 0.f;
  for (int e=s0;e<s1;e++) s += (float)mij[(long)e*DIM + d];
  xi[n*DIM+d] += s;
}

// fi += segment_sum( ef_scaled * dir[:,k] )   (eF already folded into ef)
__global__ __launch_bounds__(128) void fi_acc(const __bf16* __restrict__ ef,
                                              const float* __restrict__ dir,
                                              const int* __restrict__ row_start,
                                              float* __restrict__ fi){
  int n = blockIdx.x, d = threadIdx.x;
  int s0 = row_start[n], s1 = row_start[n+1];
  float a0=0.f,a1=0.f,a2=0.f;
  for (int e=s0;e<s1;e++){
    float s = (float)ef[(long)e*DIM+d];
    a0 += s*dir[e*3+0];
    a1 += s*dir[e*3+1];
    a2 += s*dir[e*3+2];
  }
  fi[n*384+d*3+0] += a0;
  fi[n*384+d*3+1] += a1;
  fi[n*384+d*3+2] += a2;
}

// di update + scal = sum(fi*di, -1)   (sw already folded into ephi)
__global__ __launch_bounds__(128) void discal(const float* __restrict__ Rv,
                                              const __bf16* __restrict__ ephi,
                                              const int* __restrict__ row_start,
                                              const float* __restrict__ fi,
                                              float* __restrict__ di, float* __restrict__ scal, int layer){
  int n = blockIdx.x, d = threadIdx.x;
  float Rv_ = Rv[n*DIM+d];
  float phi = 0.f;
  if (layer > 0){
    int s0 = row_start[n], s1 = row_start[n+1];
    for (int e=s0;e<s1;e++) phi += (float)ephi[(long)e*DIM+d];
  }
  float sc = 0.f;
  #pragma unroll
  for (int k=0;k<3;k++){
    float fiv = fi[n*384+d*3+k];
    float delta = Rv_*fiv;
    float dv = (layer==0) ? delta : phi*di[n*384+d*3+k] + delta;
    di[n*384+d*3+k] = dv;
    sc += fiv*dv;
  }
  scal[n*DIM+d] = sc;
}

// xi -= u * scal
__global__ void xi_update(float* __restrict__ xi, const float* __restrict__ uv,
                          const float* __restrict__ scal){
  int idx = blockIdx.x*256 + threadIdx.x;
  xi[idx] -= uv[idx]*scal[idx];
}

extern "C" void kernel_launch(void* const* d_in, const int* in_sizes, int n_in,
                              void* d_out, int out_size, void* d_ws, size_t ws_size,
                              hipStream_t stream) {
  const int*   species = (const int*)  d_in[0];
  const int*   esrc    = (const int*)  d_in[1];
  const int*   edst    = (const int*)  d_in[2];
  const float* dist    = (const float*)d_in[3];
  const float* vec     = (const float*)d_in[4];
  const float* swv     = (const float*)d_in[5];
  const float* spW     = (const float*)d_in[6];
  const float* spB     = (const float*)d_in[7];
  const float* radW    = (const float*)d_in[8];
  const float* radB    = (const float*)d_in[9];
  const float* aW1=(const float*)d_in[10], *aB1=(const float*)d_in[11], *aW2=(const float*)d_in[12], *aB2=(const float*)d_in[13];
  const float* FW1=(const float*)d_in[14], *FB1=(const float*)d_in[15], *FW2=(const float*)d_in[16], *FB2=(const float*)d_in[17];
  const float* fW1=(const float*)d_in[18], *fB1=(const float*)d_in[19], *fW2=(const float*)d_in[20], *fB2=(const float*)d_in[21];
  const float* RW1=(const float*)d_in[22], *RB1=(const float*)d_in[23], *RW2=(const float*)d_in[24], *RB2=(const float*)d_in[25];
  const float* rW1=(const float*)d_in[26], *rB1=(const float*)d_in[27], *rW2=(const float*)d_in[28], *rB2=(const float*)d_in[29];
  const float* uW1=(const float*)d_in[30], *uB1=(const float*)d_in[31], *uW2=(const float*)d_in[32], *uB2=(const float*)d_in[33];

  const long NF = (long)N_NODES*DIM;      // 1,280,000
  const long EF = (long)N_EDGES*DIM;      // 20,480,000
  float* ws   = (float*)d_ws;
  float* xi   = ws;
  float* Rv   = xi   + NF;
  float* uv   = Rv   + NF;
  float* scal = uv   + NF;
  float* fi   = scal + NF;
  float* di   = fi   + 3*NF;
  float* dir  = di   + 3*NF;
  float* rb   = dir  + 3L*N_EDGES;
  int* row_start = (int*)(rb + 16L*N_EDGES);
  char* bp = (char*)(row_start + N_NODES + 2);
  size_t off = ((size_t)(bp - (char*)d_ws) + 15) & ~(size_t)15;
  __bf16* ai   = (__bf16*)((char*)d_ws + off);
  __bf16* mij  = ai  + NF;
  __bf16* ef   = mij + EF;
  __bf16* ephi = ef  + EF;
  __bf16* wt   = ephi + EF;               // 33 x 128x128 bf16

  // bf16 transposed weights: tensor order a1,a2,F1,f1,f2,R1,R2,r1,r2,u1,u2
  WPtrs wp;
  wp.p[0]=aW1; wp.p[1]=aW2; wp.p[2]=FW1; wp.p[3]=fW1; wp.p[4]=fW2;
  wp.p[5]=RW1; wp.p[6]=RW2; wp.p[7]=rW1; wp.p[8]=rW2; wp.p[9]=uW1; wp.p[10]=uW2;
  convert_wt<<<33, 256, 0, stream>>>(wp, wt);

  seg_offsets<<<40, 256, 0, stream>>>(esrc, row_start);
  init_nodes<<<(int)(NF/256), 256, 0, stream>>>(species, spW, spB, xi, fi);
  edge_geom<<<N_EDGES/256, 256, 0, stream>>>(dist, vec, swv, dir, rb);

  const int nodeBlocks = (N_NODES + 127)/128;   // 79
  const int edgeBlocks = N_EDGES/128;           // 1250
  #define WT(t,l) (wt + (size_t)((t)*3+(l))*16384)

  for (int l=0;l<3;l++){
    const long bo = (long)l*DIM;

    // ai = mlp_a(xi)                      fp32 in, bf16 out
    mlp_k<true,false,false,false><<<nodeBlocks, 256, 0, stream>>>(
        xi, N_NODES, WT(0,l), aB1+bo, WT(1,l), aB2+bo,
        nullptr, nullptr, nullptr, nullptr, nullptr, ai);
    // mij (bf16)
    mij_kernel<<<N_EDGES/16, 256, 0, stream>>>(ai, esrc, edst, swv, rb,
                                               radW + (long)l*NBASIS*DIM, radB + bo, mij);
    // xi += segsum(mij)
    segsum_xi<<<N_NODES, 128, 0, stream>>>(mij, row_start, xi);
    // ef_scaled = mlp_f(mij) * F(mij)     bf16 in/out, fused F
    mlp_k<false,false,true,false><<<edgeBlocks, 256, 0, stream>>>(
        mij, N_EDGES, WT(3,l), fB1+bo, WT(4,l), fB2+bo,
        WT(2,l), FB1+bo, FW2+(long)l*DIM, FB2+l, nullptr, ef);
    // fi += segsum(ef_scaled * dir)
    fi_acc<<<N_NODES, 128, 0, stream>>>(ef, dir, row_start, fi);
    // ephi_scaled = mlp_r(mij) * sw       bf16 in/out, fused sw
    if (l > 0)
      mlp_k<false,false,false,true><<<edgeBlocks, 256, 0, stream>>>(
          mij, N_EDGES, WT(7,l), rB1+bo, WT(8,l), rB2+bo,
          nullptr, nullptr, nullptr, nullptr, swv, ephi);
    // Rv = mlp_R(xi)                      fp32 in/out
    mlp_k<true,true,false,false><<<nodeBlocks, 256, 0, stream>>>(
        xi, N_NODES, WT(5,l), RB1+bo, WT(6,l), RB2+bo,
        nullptr, nullptr, nullptr, nullptr, nullptr, Rv);
    // di, scal
    discal<<<N_NODES, 128, 0, stream>>>(Rv, ephi, row_start, fi, di, scal, l);
    // uv = mlp_u(xi)                      fp32 in/out
    mlp_k<true,true,false,false><<<nodeBlocks, 256, 0, stream>>>(
        xi, N_NODES, WT(9,l), uB1+bo, WT(10,l), uB2+bo,
        nullptr, nullptr, nullptr, nullptr, nullptr, uv);
    // xi -= uv*scal
    xi_update<<<(int)(NF/256), 256, 0, stream>>>(xi, uv, scal);
  }

  hipMemcpyAsync(d_out, xi, (size_t)NF*sizeof(float), hipMemcpyDeviceToDevice, stream);
}

// Round 5
// 981.083 us; speedup vs baseline: 1.2443x; 1.2443x over previous
//
#include <hip/hip_runtime.h>
#include <hip/hip_bf16.h>

#define N_NODES 10000
#define N_EDGES 160000
#define DIM     128
#define NBASIS  16
#define LDT     136   // LDS row stride (bf16): row stride 272B = 17*16 (16B aligned)

typedef __bf16 bf16x8 __attribute__((ext_vector_type(8)));
typedef __bf16 bf16x2 __attribute__((ext_vector_type(2)));
typedef float  f32x4  __attribute__((ext_vector_type(4)));

__device__ __forceinline__ float silu_f(float x){
  return x * (1.0f / (1.0f + __expf(-x)));
}
__device__ __forceinline__ f32x4 mfma16(bf16x8 a, bf16x8 b, f32x4 c){
  return __builtin_amdgcn_mfma_f32_16x16x32_bf16(a,b,c,0,0,0);
}

// ===========================================================================
// Edge MLP kernel: ef = (silu(mij@fW1+fb1)@fW2+fb2) * F(mij)
//                  ephi = (silu(mij@rW1+rb1)@rW2+rb2) * sw      (WITH_R)
// 128 edges/block, 4 waves, wave owns rows [32w,32w+32). A-frags in regs,
// reused for all GEMM1s. B direct from global (L2-hot). H + store staging in
// wave-private LDS rows -> zero __syncthreads. Coalesced bf16x8 stores
// (round-3 lesson: scattered 2B C-layout stores caused 4x write amplification).
// ===========================================================================
template<bool WITH_R>
__global__ __launch_bounds__(256,3) void mlp_fr(
    const __bf16* __restrict__ mij,
    const __bf16* __restrict__ fW1t, const float* __restrict__ fb1,
    const __bf16* __restrict__ fW2t, const float* __restrict__ fb2,
    const __bf16* __restrict__ FW1t, const float* __restrict__ Fb1,
    const float*  __restrict__ FW2v, const float* __restrict__ Fb2,
    const __bf16* __restrict__ rW1t, const float* __restrict__ rb1,
    const __bf16* __restrict__ rW2t, const float* __restrict__ rb2,
    const float*  __restrict__ swv,
    __bf16* __restrict__ ef, __bf16* __restrict__ ephi)
{
  __shared__ __bf16 sH[128*LDT];
  const int tid=threadIdx.x, lane=tid&63, wv=tid>>6, l15=lane&15, quad=lane>>4;
  const long row0 = (long)blockIdx.x*128;
  const long rA0 = row0 + wv*32 + l15, rA1 = rA0+16;

  // A-fragments: loaded once, reused for every GEMM1
  bf16x8 fa[2][4];
  #pragma unroll
  for (int kc=0;kc<4;kc++){
    int kb=kc*32+quad*8;
    fa[0][kc] = *(const bf16x8*)(mij + rA0*DIM + kb);
    fa[1][kc] = *(const bf16x8*)(mij + rA1*DIM + kb);
  }

  f32x4 acc[2][8];
  auto zacc = [&](){
    #pragma unroll
    for (int mi=0;mi<2;++mi)
      #pragma unroll
      for (int ni=0;ni<8;++ni) acc[mi][ni]=(f32x4){0.f,0.f,0.f,0.f};
  };
  auto gemmA = [&](const __bf16* __restrict__ Wt){
    #pragma unroll
    for (int kc=0;kc<4;kc++){
      int kb=kc*32+quad*8;
      #pragma unroll
      for (int ni=0;ni<8;ni++){
        bf16x8 b = *(const bf16x8*)(Wt + (long)(ni*16+l15)*DIM + kb);
        acc[0][ni]=mfma16(fa[0][kc],b,acc[0][ni]);
        acc[1][ni]=mfma16(fa[1][kc],b,acc[1][ni]);
      }
    }
  };
  auto gemmH = [&](const __bf16* __restrict__ Wt){
    #pragma unroll
    for (int kc=0;kc<4;kc++){
      int kb=kc*32+quad*8;
      bf16x8 a0=*(bf16x8*)&sH[(wv*32   +l15)*LDT+kb];
      bf16x8 a1=*(bf16x8*)&sH[(wv*32+16+l15)*LDT+kb];
      #pragma unroll
      for (int ni=0;ni<8;ni++){
        bf16x8 b = *(const bf16x8*)(Wt + (long)(ni*16+l15)*DIM + kb);
        acc[0][ni]=mfma16(a0,b,acc[0][ni]);
        acc[1][ni]=mfma16(a1,b,acc[1][ni]);
      }
    }
  };
  auto hEpi = [&](const float* __restrict__ b1){
    #pragma unroll
    for (int mi=0;mi<2;++mi)
      #pragma unroll
      for (int ni=0;ni<8;++ni){
        int col = ni*16+l15;
        float bb = b1[col];
        #pragma unroll
        for (int r=0;r<4;++r)
          sH[(wv*32+mi*16+quad*4+r)*LDT+col] = (__bf16)silu_f(acc[mi][ni][r]+bb);
      }
  };
  auto cStore = [&](const float* __restrict__ b2, const float mul[2][4],
                    __bf16* __restrict__ Y){
    #pragma unroll
    for (int mi=0;mi<2;++mi)
      #pragma unroll
      for (int ni=0;ni<8;++ni){
        int col = ni*16+l15;
        float bb = b2[col];
        #pragma unroll
        for (int r=0;r<4;++r)
          sH[(wv*32+mi*16+quad*4+r)*LDT+col] = (__bf16)((acc[mi][ni][r]+bb)*mul[mi][r]);
      }
    #pragma unroll
    for (int it=0; it<8; ++it){
      int off = it*1024 + lane*16;     // bytes within 32 rows x 256B
      int row = off>>8, col = (off&255)>>1;
      *(bf16x8*)(Y + (row0+wv*32+row)*DIM + col) = *(const bf16x8*)&sH[(wv*32+row)*LDT+col];
    }
  };

  // ---- F scalar (fused) ----
  float eF[2][4];
  zacc(); gemmA(FW1t);
  {
    float fb2v = Fb2[0];
    #pragma unroll
    for (int mi=0;mi<2;++mi)
      #pragma unroll
      for (int r=0;r<4;++r){
        float p = 0.f;
        #pragma unroll
        for (int ni=0;ni<8;++ni){
          int col = ni*16+l15;
          p += silu_f(acc[mi][ni][r] + Fb1[col]) * FW2v[col];
        }
        p += __shfl_xor(p,1); p += __shfl_xor(p,2);
        p += __shfl_xor(p,4); p += __shfl_xor(p,8);
        eF[mi][r] = p + fb2v;
      }
  }
  // ---- f MLP ----
  zacc(); gemmA(fW1t); hEpi(fb1);
  zacc(); gemmH(fW2t); cStore(fb2, eF, ef);

  if constexpr (WITH_R){
    float swr[2][4];
    #pragma unroll
    for (int mi=0;mi<2;++mi)
      #pragma unroll
      for (int r=0;r<4;++r)
        swr[mi][r] = swv[row0 + wv*32 + mi*16 + quad*4 + r];
    zacc(); gemmA(rW1t); hEpi(rb1);
    zacc(); gemmH(rW2t); cStore(rb2, swr, ephi);
  }
}

// ===========================================================================
// Node MLP: ai = bf16( silu(xi@aW1+ab1)@aW2+ab2 )   (fp32 in, bf16 out)
// ===========================================================================
__global__ __launch_bounds__(256,3) void mlp_a(
    const float* __restrict__ X, int M,
    const __bf16* __restrict__ W1t, const float* __restrict__ b1,
    const __bf16* __restrict__ W2t, const float* __restrict__ b2,
    __bf16* __restrict__ Y)
{
  __shared__ __bf16 sH[128*LDT];
  const int tid=threadIdx.x, lane=tid&63, wv=tid>>6, l15=lane&15, quad=lane>>4;
  const long row0 = (long)blockIdx.x*128;
  const long rA0 = row0 + wv*32 + l15, rA1 = rA0+16;

  bf16x8 fa[2][4];
  #pragma unroll
  for (int kc=0;kc<4;kc++){
    int kb=kc*32+quad*8;
    #pragma unroll
    for (int mi=0;mi<2;++mi){
      long rg = mi? rA1 : rA0;
      bf16x8 a;
      #pragma unroll
      for (int i=0;i<8;i++) a[i]=(__bf16)0.f;
      if (rg < M){
        float4 u0 = *(const float4*)(X + rg*DIM + kb);
        float4 u1 = *(const float4*)(X + rg*DIM + kb + 4);
        a[0]=(__bf16)u0.x;a[1]=(__bf16)u0.y;a[2]=(__bf16)u0.z;a[3]=(__bf16)u0.w;
        a[4]=(__bf16)u1.x;a[5]=(__bf16)u1.y;a[6]=(__bf16)u1.z;a[7]=(__bf16)u1.w;
      }
      fa[mi][kc]=a;
    }
  }

  f32x4 acc[2][8];
  #pragma unroll
  for (int mi=0;mi<2;++mi)
    #pragma unroll
    for (int ni=0;ni<8;++ni) acc[mi][ni]=(f32x4){0.f,0.f,0.f,0.f};
  #pragma unroll
  for (int kc=0;kc<4;kc++){
    int kb=kc*32+quad*8;
    #pragma unroll
    for (int ni=0;ni<8;ni++){
      bf16x8 b = *(const bf16x8*)(W1t + (long)(ni*16+l15)*DIM + kb);
      acc[0][ni]=mfma16(fa[0][kc],b,acc[0][ni]);
      acc[1][ni]=mfma16(fa[1][kc],b,acc[1][ni]);
    }
  }
  #pragma unroll
  for (int mi=0;mi<2;++mi)
    #pragma unroll
    for (int ni=0;ni<8;++ni){
      int col = ni*16+l15; float bb=b1[col];
      #pragma unroll
      for (int r=0;r<4;++r)
        sH[(wv*32+mi*16+quad*4+r)*LDT+col]=(__bf16)silu_f(acc[mi][ni][r]+bb);
    }
  #pragma unroll
  for (int mi=0;mi<2;++mi)
    #pragma unroll
    for (int ni=0;ni<8;++ni) acc[mi][ni]=(f32x4){0.f,0.f,0.f,0.f};
  #pragma unroll
  for (int kc=0;kc<4;kc++){
    int kb=kc*32+quad*8;
    bf16x8 a0=*(bf16x8*)&sH[(wv*32   +l15)*LDT+kb];
    bf16x8 a1=*(bf16x8*)&sH[(wv*32+16+l15)*LDT+kb];
    #pragma unroll
    for (int ni=0;ni<8;ni++){
      bf16x8 b = *(const bf16x8*)(W2t + (long)(ni*16+l15)*DIM + kb);
      acc[0][ni]=mfma16(a0,b,acc[0][ni]);
      acc[1][ni]=mfma16(a1,b,acc[1][ni]);
    }
  }
  #pragma unroll
  for (int mi=0;mi<2;++mi)
    #pragma unroll
    for (int ni=0;ni<8;++ni){
      int col = ni*16+l15; float bb=b2[col];
      #pragma unroll
      for (int r=0;r<4;++r)
        sH[(wv*32+mi*16+quad*4+r)*LDT+col]=(__bf16)(acc[mi][ni][r]+bb);
    }
  #pragma unroll
  for (int it=0; it<8; ++it){
    int off = it*1024 + lane*16;
    int row = off>>8, col=(off&255)>>1;
    long rg = row0 + wv*32 + row;
    if (rg < M)
      *(bf16x8*)(Y + rg*DIM + col) = *(const bf16x8*)&sH[(wv*32+row)*LDT+col];
  }
}

// ===========================================================================
// Node MLPs R and u in one kernel (read xi once). fp32 out, C-layout direct
// stores (full 64B sectors: 16 lanes x 4B).
// ===========================================================================
__global__ __launch_bounds__(256,3) void mlp_Ru(
    const float* __restrict__ X, int M,
    const __bf16* __restrict__ RW1t, const float* __restrict__ Rb1,
    const __bf16* __restrict__ RW2t, const float* __restrict__ Rb2,
    const __bf16* __restrict__ uW1t, const float* __restrict__ ub1,
    const __bf16* __restrict__ uW2t, const float* __restrict__ ub2,
    float* __restrict__ Rv, float* __restrict__ uv)
{
  __shared__ __bf16 sH[128*LDT];
  const int tid=threadIdx.x, lane=tid&63, wv=tid>>6, l15=lane&15, quad=lane>>4;
  const long row0 = (long)blockIdx.x*128;
  const long rA0 = row0 + wv*32 + l15, rA1 = rA0+16;

  bf16x8 fa[2][4];
  #pragma unroll
  for (int kc=0;kc<4;kc++){
    int kb=kc*32+quad*8;
    #pragma unroll
    for (int mi=0;mi<2;++mi){
      long rg = mi? rA1 : rA0;
      bf16x8 a;
      #pragma unroll
      for (int i=0;i<8;i++) a[i]=(__bf16)0.f;
      if (rg < M){
        float4 u0 = *(const float4*)(X + rg*DIM + kb);
        float4 u1 = *(const float4*)(X + rg*DIM + kb + 4);
        a[0]=(__bf16)u0.x;a[1]=(__bf16)u0.y;a[2]=(__bf16)u0.z;a[3]=(__bf16)u0.w;
        a[4]=(__bf16)u1.x;a[5]=(__bf16)u1.y;a[6]=(__bf16)u1.z;a[7]=(__bf16)u1.w;
      }
      fa[mi][kc]=a;
    }
  }

  f32x4 acc[2][8];
  auto zacc = [&](){
    #pragma unroll
    for (int mi=0;mi<2;++mi)
      #pragma unroll
      for (int ni=0;ni<8;++ni) acc[mi][ni]=(f32x4){0.f,0.f,0.f,0.f};
  };
  auto gemmA = [&](const __bf16* __restrict__ Wt){
    #pragma unroll
    for (int kc=0;kc<4;kc++){
      int kb=kc*32+quad*8;
      #pragma unroll
      for (int ni=0;ni<8;ni++){
        bf16x8 b = *(const bf16x8*)(Wt + (long)(ni*16+l15)*DIM + kb);
        acc[0][ni]=mfma16(fa[0][kc],b,acc[0][ni]);
        acc[1][ni]=mfma16(fa[1][kc],b,acc[1][ni]);
      }
    }
  };
  auto gemmH = [&](const __bf16* __restrict__ Wt){
    #pragma unroll
    for (int kc=0;kc<4;kc++){
      int kb=kc*32+quad*8;
      bf16x8 a0=*(bf16x8*)&sH[(wv*32   +l15)*LDT+kb];
      bf16x8 a1=*(bf16x8*)&sH[(wv*32+16+l15)*LDT+kb];
      #pragma unroll
      for (int ni=0;ni<8;ni++){
        bf16x8 b = *(const bf16x8*)(Wt + (long)(ni*16+l15)*DIM + kb);
        acc[0][ni]=mfma16(a0,b,acc[0][ni]);
        acc[1][ni]=mfma16(a1,b,acc[1][ni]);
      }
    }
  };
  auto hEpi = [&](const float* __restrict__ b1){
    #pragma unroll
    for (int mi=0;mi<2;++mi)
      #pragma unroll
      for (int ni=0;ni<8;++ni){
        int col = ni*16+l15; float bb=b1[col];
        #pragma unroll
        for (int r=0;r<4;++r)
          sH[(wv*32+mi*16+quad*4+r)*LDT+col]=(__bf16)silu_f(acc[mi][ni][r]+bb);
      }
  };
  auto cStoreF = [&](const float* __restrict__ b2, float* __restrict__ Y){
    #pragma unroll
    for (int mi=0;mi<2;++mi)
      #pragma unroll
      for (int ni=0;ni<8;++ni){
        int col = ni*16+l15; float bb=b2[col];
        #pragma unroll
        for (int r=0;r<4;++r){
          long rg = row0 + wv*32 + mi*16 + quad*4 + r;
          if (rg < M) Y[rg*DIM+col] = acc[mi][ni][r]+bb;
        }
      }
  };

  zacc(); gemmA(RW1t); hEpi(Rb1);
  zacc(); gemmH(RW2t); cStoreF(Rb2, Rv);
  zacc(); gemmA(uW1t); hEpi(ub1);
  zacc(); gemmH(uW2t); cStoreF(ub2, uv);
}

// ---------------------------------------------------------------------------
// Convert + transpose fp32 W[k][n] -> bf16 Wt[n][k]. One block per matrix.
// ---------------------------------------------------------------------------
struct WPtrs { const float* p[11]; };

__global__ __launch_bounds__(256) void convert_wt(WPtrs wp, __bf16* __restrict__ dst){
  __shared__ __bf16 s[128*129];
  int mat = blockIdx.x;          // t*3 + l
  int t = mat/3, l = mat%3;
  const float* src = wp.p[t] + (size_t)l*16384;
  __bf16* out = dst + (size_t)mat*16384;
  for (int it=0; it<64; ++it){
    int idx = it*256 + threadIdx.x;
    int k = idx>>7, n = idx&127;
    s[k*129+n] = (__bf16)src[idx];
  }
  __syncthreads();
  for (int it=0; it<64; ++it){
    int idx = it*256 + threadIdx.x;
    int n = idx>>7, k = idx&127;
    out[idx] = s[k*129+n];
  }
}

// row_start[n] = lower_bound(edge_src, n)  (edge_src is sorted)
__global__ void seg_offsets(const int* __restrict__ esrc, int* __restrict__ row_start){
  int t = blockIdx.x*256 + threadIdx.x;
  if (t > N_NODES) return;
  int lo = 0, hi = N_EDGES;
  while (lo < hi){ int mid = (lo+hi)>>1; if (esrc[mid] < t) lo = mid+1; else hi = mid; }
  row_start[t] = lo;
}

// xi init + fi zero
__global__ void init_nodes(const int* __restrict__ species,
                           const float* __restrict__ spW, const float* __restrict__ spB,
                           float* __restrict__ xi, float* __restrict__ fi){
  int idx = blockIdx.x*256 + threadIdx.x;   // < N*128
  int n = idx >> 7, d = idx & 127;
  xi[idx] = spW[species[n]*DIM + d] + spB[d];
  fi[n*384 + d*3 + 0] = 0.f;
  fi[n*384 + d*3 + 1] = 0.f;
  fi[n*384 + d*3 + 2] = 0.f;
}

// dir = vec/dist*sw ; rb = exp(-eta*(d-c_j)^2)
__global__ void edge_geom(const float* __restrict__ dist, const float* __restrict__ vec,
                          const float* __restrict__ swv,
                          float* __restrict__ dir, float* __restrict__ rb){
  int e = blockIdx.x*256 + threadIdx.x;
  if (e >= N_EDGES) return;
  float d = dist[e];
  float s = swv[e];
  float inv = s / d;
  dir[e*3+0] = vec[e*3+0]*inv;
  dir[e*3+1] = vec[e*3+1]*inv;
  dir[e*3+2] = vec[e*3+2]*inv;
  const float eta = (16.0f/5.0f)*(16.0f/5.0f);
  #pragma unroll
  for (int j=0;j<NBASIS;j++){
    float c = (float)j * (5.0f/15.0f);
    float t = d - c;
    rb[e*NBASIS + j] = __expf(-eta*t*t);
  }
}

// mij = ai[src]*ai[dst]*(rb@radW + radB)*sw ; 64 edges/block; bf16 in/out
__global__ __launch_bounds__(256) void mij_kernel(
    const __bf16* __restrict__ ai, const int* __restrict__ esrc, const int* __restrict__ edst,
    const float* __restrict__ swv, const float* __restrict__ rb,
    const float* __restrict__ radW, const float* __restrict__ radB,
    __bf16* __restrict__ mij)
{
  __shared__ float sRW[NBASIS*DIM];
  __shared__ float sRB[DIM];
  __shared__ float sRb[64*NBASIS];
  __shared__ int   sS[64], sD[64];
  __shared__ float sSw[64];
  int tid = threadIdx.x;
  int e0 = blockIdx.x * 64;
  #pragma unroll
  for (int i=0;i<2;i++)
    *(float4*)(sRW + (i*256+tid)*4) = *(const float4*)(radW + (i*256+tid)*4);
  *(float4*)(sRb + tid*4) = *(const float4*)(rb + (long)e0*NBASIS + tid*4);
  if (tid < DIM) sRB[tid] = radB[tid];
  if (tid < 64){
    sS[tid]  = esrc[e0+tid];
    sD[tid]  = edst[e0+tid];
    sSw[tid] = swv[e0+tid];
  }
  __syncthreads();
  #pragma unroll
  for (int i=0;i<16;i++){
    int el = i*4 + (tid>>6);
    int d  = (tid&63)*2;
    bf16x2 as = *(const bf16x2*)(ai + (long)sS[el]*DIM + d);
    bf16x2 ad = *(const bf16x2*)(ai + (long)sD[el]*DIM + d);
    float acc0 = 0.f, acc1 = 0.f;
    #pragma unroll
    for (int j=0;j<NBASIS;j++){
      float rbv = sRb[el*NBASIS+j];
      acc0 += rbv*sRW[j*DIM+d];
      acc1 += rbv*sRW[j*DIM+d+1];
    }
    float sw_ = sSw[el];
    bf16x2 m;
    m[0] = (__bf16)((float)as[0]*(float)ad[0]*(acc0+sRB[d  ])*sw_);
    m[1] = (__bf16)((float)as[1]*(float)ad[1]*(acc1+sRB[d+1])*sw_);
    *(bf16x2*)(mij + (long)(e0+el)*DIM + d) = m;
  }
}

// xi += segment_sum(mij)
__global__ __launch_bounds__(128) void segsum_xi(const __bf16* __restrict__ mij,
                                                 const int* __restrict__ row_start,
                                                 float* __restrict__ xi){
  int n = blockIdx.x, d = threadIdx.x;
  int s0 = row_start[n], s1 = row_start[n+1];
  float s = 0.f;
  for (int e=s0;e<s1;e++) s += (float)mij[(long)e*DIM + d];
  xi[n*DIM+d] += s;
}

// merged fi_acc + discal: fi += segsum(ef*dir); phi = segsum(ephi); di, scal
__global__ __launch_bounds__(128) void node_update(
    const __bf16* __restrict__ ef, const __bf16* __restrict__ ephi,
    const float* __restrict__ dir, const int* __restrict__ row_start,
    const float* __restrict__ Rv,
    float* __restrict__ fi, float* __restrict__ di, float* __restrict__ scal,
    int layer)
{
  int n = blockIdx.x, d = threadIdx.x;
  int s0 = row_start[n], s1 = row_start[n+1];
  float a0=0.f,a1=0.f,a2=0.f, phi=0.f;
  for (int e=s0;e<s1;e++){
    float s = (float)ef[(long)e*DIM+d];
    a0 += s*dir[e*3+0];
    a1 += s*dir[e*3+1];
    a2 += s*dir[e*3+2];
    if (layer > 0) phi += (float)ephi[(long)e*DIM+d];
  }
  float f0 = fi[n*384+d*3+0]+a0;
  float f1 = fi[n*384+d*3+1]+a1;
  float f2 = fi[n*384+d*3+2]+a2;
  fi[n*384+d*3+0]=f0; fi[n*384+d*3+1]=f1; fi[n*384+d*3+2]=f2;
  float Rv_ = Rv[n*DIM+d];
  float sc = 0.f;
  float fv[3] = {f0,f1,f2};
  #pragma unroll
  for (int k=0;k<3;k++){
    float delta = Rv_*fv[k];
    float dv = (layer==0) ? delta : phi*di[n*384+d*3+k] + delta;
    di[n*384+d*3+k] = dv;
    sc += fv[k]*dv;
  }
  scal[n*DIM+d] = sc;
}

// xi -= u * scal
__global__ void xi_update(float* __restrict__ xi, const float* __restrict__ uv,
                          const float* __restrict__ scal){
  int idx = blockIdx.x*256 + threadIdx.x;
  xi[idx] -= uv[idx]*scal[idx];
}

extern "C" void kernel_launch(void* const* d_in, const int* in_sizes, int n_in,
                              void* d_out, int out_size, void* d_ws, size_t ws_size,
                              hipStream_t stream) {
  const int*   species = (const int*)  d_in[0];
  const int*   esrc    = (const int*)  d_in[1];
  const int*   edst    = (const int*)  d_in[2];
  const float* dist    = (const float*)d_in[3];
  const float* vec     = (const float*)d_in[4];
  const float* swv     = (const float*)d_in[5];
  const float* spW     = (const float*)d_in[6];
  const float* spB     = (const float*)d_in[7];
  const float* radW    = (const float*)d_in[8];
  const float* radB    = (const float*)d_in[9];
  const float* aW1=(const float*)d_in[10], *aB1=(const float*)d_in[11], *aW2=(const float*)d_in[12], *aB2=(const float*)d_in[13];
  const float* FW1=(const float*)d_in[14], *FB1=(const float*)d_in[15], *FW2=(const float*)d_in[16], *FB2=(const float*)d_in[17];
  const float* fW1=(const float*)d_in[18], *fB1=(const float*)d_in[19], *fW2=(const float*)d_in[20], *fB2=(const float*)d_in[21];
  const float* RW1=(const float*)d_in[22], *RB1=(const float*)d_in[23], *RW2=(const float*)d_in[24], *RB2=(const float*)d_in[25];
  const float* rW1=(const float*)d_in[26], *rB1=(const float*)d_in[27], *rW2=(const float*)d_in[28], *rB2=(const float*)d_in[29];
  const float* uW1=(const float*)d_in[30], *uB1=(const float*)d_in[31], *uW2=(const float*)d_in[32], *uB2=(const float*)d_in[33];

  const long NF = (long)N_NODES*DIM;      // 1,280,000
  const long EF = (long)N_EDGES*DIM;      // 20,480,000
  float* ws   = (float*)d_ws;
  float* xi   = ws;
  float* Rv   = xi   + NF;
  float* uv   = Rv   + NF;
  float* scal = uv   + NF;
  float* fi   = scal + NF;
  float* di   = fi   + 3*NF;
  float* dir  = di   + 3*NF;
  float* rb   = dir  + 3L*N_EDGES;
  int* row_start = (int*)(rb + 16L*N_EDGES);
  char* bp = (char*)(row_start + N_NODES + 2);
  size_t off = ((size_t)(bp - (char*)d_ws) + 15) & ~(size_t)15;
  __bf16* ai   = (__bf16*)((char*)d_ws + off);
  __bf16* mij  = ai  + NF;
  __bf16* ef   = mij + EF;
  __bf16* ephi = ef  + EF;
  __bf16* wt   = ephi + EF;               // 33 x 128x128 bf16

  // bf16 transposed weights: tensor order a1,a2,F1,f1,f2,R1,R2,r1,r2,u1,u2
  WPtrs wp;
  wp.p[0]=aW1; wp.p[1]=aW2; wp.p[2]=FW1; wp.p[3]=fW1; wp.p[4]=fW2;
  wp.p[5]=RW1; wp.p[6]=RW2; wp.p[7]=rW1; wp.p[8]=rW2; wp.p[9]=uW1; wp.p[10]=uW2;
  convert_wt<<<33, 256, 0, stream>>>(wp, wt);

  seg_offsets<<<40, 256, 0, stream>>>(esrc, row_start);
  init_nodes<<<(int)(NF/256), 256, 0, stream>>>(species, spW, spB, xi, fi);
  edge_geom<<<N_EDGES/256, 256, 0, stream>>>(dist, vec, swv, dir, rb);

  const int nodeBlocks = (N_NODES + 127)/128;   // 79
  const int edgeBlocks = N_EDGES/128;           // 1250
  #define WT(t,l) (wt + (size_t)((t)*3+(l))*16384)

  for (int l=0;l<3;l++){
    const long bo = (long)l*DIM;

    // ai = mlp_a(xi)
    mlp_a<<<nodeBlocks, 256, 0, stream>>>(xi, N_NODES, WT(0,l), aB1+bo, WT(1,l), aB2+bo, ai);
    // mij (bf16)
    mij_kernel<<<N_EDGES/64, 256, 0, stream>>>(ai, esrc, edst, swv, rb,
                                               radW + (long)l*NBASIS*DIM, radB + bo, mij);
    // xi += segsum(mij)
    segsum_xi<<<N_NODES, 128, 0, stream>>>(mij, row_start, xi);
    // ef = f(mij)*F(mij)  [+ ephi = r(mij)*sw]
    if (l == 0)
      mlp_fr<false><<<edgeBlocks, 256, 0, stream>>>(
          mij, WT(3,l), fB1+bo, WT(4,l), fB2+bo,
          WT(2,l), FB1+bo, FW2+(long)l*DIM, FB2+l,
          nullptr, nullptr, nullptr, nullptr, nullptr, ef, nullptr);
    else
      mlp_fr<true><<<edgeBlocks, 256, 0, stream>>>(
          mij, WT(3,l), fB1+bo, WT(4,l), fB2+bo,
          WT(2,l), FB1+bo, FW2+(long)l*DIM, FB2+l,
          WT(7,l), rB1+bo, WT(8,l), rB2+bo, swv, ef, ephi);
    // Rv, uv
    mlp_Ru<<<nodeBlocks, 256, 0, stream>>>(xi, N_NODES,
        WT(5,l), RB1+bo, WT(6,l), RB2+bo,
        WT(9,l), uB1+bo, WT(10,l), uB2+bo, Rv, uv);
    // fi, di, scal
    node_update<<<N_NODES, 128, 0, stream>>>(ef, ephi, dir, row_start, Rv,
                                             fi, di, scal, l);
    // xi -= uv*scal
    xi_update<<<(int)(NF/256), 256, 0, stream>>>(xi, uv, scal);
  }

  hipMemcpyAsync(d_out, xi, (size_t)NF*sizeof(float), hipMemcpyDeviceToDevice, stream);
}